// Round 8
// baseline (891.793 us; speedup 1.0000x reference)
//
#include <hip/hip_runtime.h>

#define N_VOX 50000
#define BATCH 2
#define DD 8
#define HH 160
#define WW 160
#define PD 10
#define PH 162
#define PW 162
#define KK 27
#define NCELL (BATCH*DD*HH*WW)         // 409600 = 400*1024
#define GRID_ELEMS (BATCH*PD*PH*PW)    // 524880
#define OUT_ELEMS (BATCH*128*DD*HH*WW) // 52,428,800

typedef __attribute__((ext_vector_type(8))) short short8v;
typedef __attribute__((ext_vector_type(4))) float float4v;

__device__ inline unsigned short f2bf(float f) {
    unsigned u = __float_as_uint(f);
    u += 0x7FFFu + ((u >> 16) & 1u);
    return (unsigned short)(u >> 16);
}

// ============ spatial sort: occupancy flags -> prefix sum -> permutation ====
__global__ void k_flags(const int* __restrict__ coors, int* __restrict__ flags) {
    int n = blockIdx.x * 256 + threadIdx.x;
    if (n >= N_VOX) return;
    int b = coors[n*4+0], z = coors[n*4+1], y = coors[n*4+2], x = coors[n*4+3];
    flags[((b*DD + z)*HH + y)*WW + x] = 1;
}

__global__ void k_scan1(const int* __restrict__ flags, int* __restrict__ scanout,
                        int* __restrict__ bsums) {
    __shared__ int s[256];
    int t = threadIdx.x, blk = blockIdx.x;
    int4 v = ((const int4*)(flags + blk*1024))[t];
    int tsum = v.x + v.y + v.z + v.w;
    s[t] = tsum; __syncthreads();
    for (int off = 1; off < 256; off <<= 1) {
        int x = (t >= off) ? s[t-off] : 0;
        __syncthreads(); s[t] += x; __syncthreads();
    }
    int excl = s[t] - tsum;
    int4 o; o.x = excl; o.y = excl + v.x; o.z = o.y + v.y; o.w = o.z + v.z;
    ((int4*)(scanout + blk*1024))[t] = o;
    if (t == 255) bsums[blk] = s[255];
}

__global__ void k_scan2(int* __restrict__ bsums) {
    __shared__ int s[512];
    int t = threadIdx.x;
    int orig = (t < 400) ? bsums[t] : 0;
    s[t] = orig; __syncthreads();
    for (int off = 1; off < 512; off <<= 1) {
        int x = (t >= off) ? s[t-off] : 0;
        __syncthreads(); s[t] += x; __syncthreads();
    }
    if (t < 400) bsums[t] = s[t] - orig;
}

__global__ void k_pos(const int* __restrict__ coors, const int* __restrict__ scanout,
                      const int* __restrict__ bsums, int* __restrict__ pos_of,
                      int* __restrict__ vox_at) {
    int n = blockIdx.x * 256 + threadIdx.x;
    if (n >= N_VOX) return;
    int b = coors[n*4+0], z = coors[n*4+1], y = coors[n*4+2], x = coors[n*4+3];
    int lin = ((b*DD + z)*HH + y)*WW + x;
    int pos = scanout[lin] + bsums[lin >> 10];
    pos_of[n] = pos;
    vox_at[pos] = n;
}

__global__ void k_gridP(const int* __restrict__ coors, const int* __restrict__ pos_of,
                        int* __restrict__ gridP) {
    int n = blockIdx.x * 256 + threadIdx.x;
    if (n >= N_VOX) return;
    int b = coors[n*4+0], z = coors[n*4+1], y = coors[n*4+2], x = coors[n*4+3];
    gridP[((b*PD + z+1)*PH + (y+1))*PW + (x+1)] = pos_of[n];
}

// iterate permuted index -> coalesced nbrP writes
__global__ void k_nbrP(const int* __restrict__ coors, const int* __restrict__ vox_at,
                       const int* __restrict__ gridP, int* __restrict__ nbrP) {
    int i = blockIdx.x * 256 + threadIdx.x;
    if (i >= N_VOX) return;
    int n = vox_at[i];
    int b = coors[n*4+0], z = coors[n*4+1]+1, y = coors[n*4+2]+1, x = coors[n*4+3]+1;
    int k = 0;
    for (int dz = -1; dz <= 1; ++dz)
        for (int dy = -1; dy <= 1; ++dy)
            for (int dx = -1; dx <= 1; ++dx) {
                int g = gridP[((b*PD + z+dz)*PH + (y+dy))*PW + (x+dx)];
                nbrP[k*N_VOX + i] = (g >= 0) ? g : N_VOX;
                ++k;
            }
}

// ============ phi: [N_VOX+1][4*CIN] bf16 (permuted rows); pad row = phi(0) ==
__global__ void k_phi0(const float* __restrict__ vf, const int* __restrict__ vox_at,
                       unsigned short* __restrict__ phi) {
    int e = blockIdx.x * 256 + threadIdx.x;
    if (e >= (N_VOX + 1) * 16) return;
    int i = e / 16, c = e % 16;
    float x = 0.f;
    if (i < N_VOX) x = vf[(size_t)vox_at[i] * 16 + c];
    float sig = 1.f / (1.f + __expf(-x));
    ushort4 p;
    p.x = f2bf(x * sig);
    p.y = f2bf(__expf(-(x + 1.f) * (x + 1.f)));
    p.z = f2bf(__expf(-x * x));
    p.w = f2bf(__expf(-(x - 1.f) * (x - 1.f)));
    *(ushort4*)&phi[(size_t)e * 4] = p;
}

// ============ all 5 layers' weight swizzle in ONE dispatch ============
struct WswzArgs {
    const float* wb[5];
    const float* ws[5];
    unsigned short* dst[5];
};
__global__ void k_wswz_all(WswzArgs a) {
    constexpr int off[6]   = {0, 27648, 82944, 304128, 746496, 1631232};
    constexpr int lgCI4[5] = {6, 6, 7, 8, 8};
    constexpr int lgCO[5]  = {4, 5, 6, 6, 7};
    int e = blockIdx.x * 256 + threadIdx.x;
    if (e >= off[5]) return;
    int L = 0;
    #pragma unroll
    for (int i = 1; i < 5; ++i) L += (e >= off[i]);
    int el = e - off[L];
    int CIN4 = 1 << lgCI4[L], COUT = 1 << lgCO[L], CIN = CIN4 >> 2;
    int j8   = el & 7;
    int rest = el >> 3;
    int o    = rest & (COUT - 1);
    int kb   = rest >> lgCO[L];
    int kabs = kb * 8 + j8;
    int k  = kabs >> lgCI4[L];
    int c4 = kabs & (CIN4 - 1);
    int c = c4 >> 2, jj = c4 & 3;
    float v = (jj == 0) ? a.wb[L][(k * CIN + c) * COUT + o]
                        : a.ws[L][((k * CIN + c) * 3 + (jj - 1)) * COUT + o];
    a.dst[L][el] = f2bf(v);
}

// ============ barrier-free MFMA conv, split-K (SK partial buffers) ==========
// Block (mb,h,sk): 128 voxel rows x COUTH cols, stage range sk of SK.
// R4's proven shape: in-loop B from global (L2), A register-prefetched one
// k-offset ahead. Partial sums written atomically-free to preA/preB.
template<int CIN, int COUT, int NSPL, int SK>
__global__ __launch_bounds__(256) void k_conv_mfma(
    const unsigned short* __restrict__ phi,   // [(N_VOX+1), 4*CIN] bf16
    const int*            __restrict__ nbrP,  // [KK, N_VOX] permuted, pad = N_VOX
    const unsigned short* __restrict__ Wsw,   // [Ktot/8, COUT, 8] bf16
    float*                __restrict__ preA,  // [N_VOX, COUT] partial sk=0
    float*                __restrict__ preB)  // [N_VOX, COUT] partial sk=1
{
    constexpr int CIN4   = CIN * 4;
    constexpr int BK     = 64;
    constexpr int SPK    = CIN4 / BK;          // 1,1,2,4,4
    constexpr int NSTAGE = KK * SPK;
    constexpr int COUTH  = COUT / NSPL;
    constexpr int NFW    = COUTH / 16;         // 1..4
    constexpr int NMB    = (N_VOX + 127) / 128;
    constexpr int NBLK   = NMB * NSPL * SK;
    constexpr int PERX   = (NBLK + 7) / 8;

    int lb = blockIdx.x;
    int linear = (lb & 7) * PERX + (lb >> 3);  // XCD swizzle: same-mb contiguous
    if (linear >= NBLK) return;
    const int mb = linear / (NSPL * SK);
    const int rem = linear % (NSPL * SK);
    const int h = rem / SK, sk = rem % SK;

    const int s0 = (sk * NSTAGE) / SK;
    const int s1 = ((sk + 1) * NSTAGE) / SK;

    const int t = threadIdx.x, lane = t & 63, wv = t >> 6;
    const int l15 = lane & 15, q = lane >> 4;
    const int base = mb * 128;
    const int vg0 = base + wv * 32 + l15, vg1 = vg0 + 16;
    const int ob = h * COUTH;

    // per-lane B base: kb = s*8 + kk*4 + q ; o = ob + nf*16 + l15
    const unsigned short* bp = Wsw + (size_t)(q * COUT + ob + l15) * 8;

    float4v acc[2][NFW];
    #pragma unroll
    for (int mi = 0; mi < 2; ++mi)
        #pragma unroll
        for (int nf = 0; nf < NFW; ++nf)
            acc[mi][nf] = (float4v){0.f, 0.f, 0.f, 0.f};

    int rows[2], rowsN[2];
    short8v A[2][2], An[2][2];

    const int k0 = s0 / SPK;
    rows[0]  = (vg0 < N_VOX) ? nbrP[k0 * N_VOX + vg0] : N_VOX;
    rows[1]  = (vg1 < N_VOX) ? nbrP[k0 * N_VOX + vg1] : N_VOX;
    rowsN[0] = (vg0 < N_VOX && k0 + 1 < KK) ? nbrP[(k0 + 1) * N_VOX + vg0] : N_VOX;
    rowsN[1] = (vg1 < N_VOX && k0 + 1 < KK) ? nbrP[(k0 + 1) * N_VOX + vg1] : N_VOX;
    {
        const int c4s = (s0 % SPK) * BK;
        const unsigned short* p0 = phi + (size_t)rows[0] * CIN4 + c4s + q * 8;
        const unsigned short* p1 = phi + (size_t)rows[1] * CIN4 + c4s + q * 8;
        A[0][0] = *(const short8v*)p0;        A[0][1] = *(const short8v*)p1;
        A[1][0] = *(const short8v*)(p0 + 32); A[1][1] = *(const short8v*)(p1 + 32);
    }

    for (int s = s0; s < s1; ++s) {
        if (s + 1 < s1) {                       // prefetch next stage's A
            const int sp = s + 1;
            if (sp % SPK == 0) { rows[0] = rowsN[0]; rows[1] = rowsN[1]; }
            const int c4n = (sp % SPK) * BK;
            const unsigned short* p0 = phi + (size_t)rows[0] * CIN4 + c4n + q * 8;
            const unsigned short* p1 = phi + (size_t)rows[1] * CIN4 + c4n + q * 8;
            An[0][0] = *(const short8v*)p0;        An[0][1] = *(const short8v*)p1;
            An[1][0] = *(const short8v*)(p0 + 32); An[1][1] = *(const short8v*)(p1 + 32);
            if (sp % SPK == 0) {
                int k2 = sp / SPK + 1;
                if (k2 < KK) {
                    rowsN[0] = (vg0 < N_VOX) ? nbrP[k2 * N_VOX + vg0] : N_VOX;
                    rowsN[1] = (vg1 < N_VOX) ? nbrP[k2 * N_VOX + vg1] : N_VOX;
                }
            }
        }
        // in-loop B loads (coalesced, L2-resident) + MFMAs
        #pragma unroll
        for (int kk = 0; kk < 2; ++kk) {
            #pragma unroll
            for (int nf = 0; nf < NFW; ++nf) {
                short8v bfr = *(const short8v*)(bp +
                    ((size_t)(s * 8 + kk * 4) * COUT + nf * 16) * 8);
                acc[0][nf] = __builtin_amdgcn_mfma_f32_16x16x32_bf16(A[kk][0], bfr, acc[0][nf], 0, 0, 0);
                acc[1][nf] = __builtin_amdgcn_mfma_f32_16x16x32_bf16(A[kk][1], bfr, acc[1][nf], 0, 0, 0);
            }
        }
        #pragma unroll
        for (int kk = 0; kk < 2; ++kk) { A[kk][0] = An[kk][0]; A[kk][1] = An[kk][1]; }
    }

    float* preH = sk ? preB : preA;
    // C/D layout: col(o)=lane&15, row(m)=(lane>>4)*4+r  [measured m89]
    #pragma unroll
    for (int mi = 0; mi < 2; ++mi)
        #pragma unroll
        for (int nf = 0; nf < NFW; ++nf)
            #pragma unroll
            for (int r = 0; r < 4; ++r) {
                int v = base + wv * 32 + mi * 16 + q * 4 + r;
                if (v < N_VOX)
                    preH[(size_t)v * COUT + ob + nf * 16 + l15] = acc[mi][nf][r];
            }
}

// ============ BN stats over preA+preB ============
template<int COUT>
__global__ void k_bnstats2(const float* __restrict__ preA, const float* __restrict__ preB,
                           float* __restrict__ sums) {
    __shared__ float s1[256], s2[256];
    int t = threadIdx.x;
    int stride = gridDim.x * 256;
    float a = 0.f, b = 0.f;
    for (int e = blockIdx.x*256 + t; e < N_VOX*COUT; e += stride) {
        float v = preA[e] + preB[e];
        a += v; b += v*v;
    }
    s1[t] = a; s2[t] = b;
    __syncthreads();
    if (t < COUT) {   // 256 % COUT == 0 and stride % COUT == 0
        float x1 = 0.f, x2 = 0.f;
        for (int j = t; j < 256; j += COUT) { x1 += s1[j]; x2 += s2[j]; }
        atomicAdd(&sums[t], x1);
        atomicAdd(&sums[COUT + t], x2);
    }
}

// ============ BN apply (sums halves) fused with next-layer phi =============
template<int COUT>
__global__ void k_bnapply_phi(const float* __restrict__ preA, const float* __restrict__ preB,
                              const float* __restrict__ sums,
                              const float* __restrict__ gm, const float* __restrict__ bt,
                              unsigned short* __restrict__ phi) {
    __shared__ float sc[COUT], sh[COUT];
    int t = threadIdx.x;
    if (t < COUT) {
        float mu  = sums[t] * (1.f / N_VOX);
        float var = sums[COUT + t] * (1.f / N_VOX) - mu*mu;
        float s = rsqrtf(var + 1e-3f) * gm[t];
        sc[t] = s;
        sh[t] = bt[t] - mu * s;
    }
    __syncthreads();
    int tot = (N_VOX + 1) * COUT;
    for (int e = blockIdx.x*256 + t; e < tot; e += gridDim.x*256) {
        int i = e / COUT, c = e % COUT;
        float x = 0.f;
        if (i < N_VOX) {
            float v = preA[(size_t)i*COUT + c] + preB[(size_t)i*COUT + c];
            x = fmaxf(v * sc[c] + sh[c], 0.f);
        }
        float sig = 1.f / (1.f + __expf(-x));
        ushort4 p;
        p.x = f2bf(x * sig);
        p.y = f2bf(__expf(-(x + 1.f) * (x + 1.f)));
        p.z = f2bf(__expf(-x * x));
        p.w = f2bf(__expf(-(x - 1.f) * (x - 1.f)));
        *(ushort4*)&phi[(size_t)e * 4] = p;
    }
}

template<int COUT>
__global__ void k_bnapply_f32(float* __restrict__ preA, const float* __restrict__ preB,
                              const float* __restrict__ sums,
                              const float* __restrict__ gm, const float* __restrict__ bt) {
    __shared__ float sc[COUT], sh[COUT];
    int t = threadIdx.x;
    if (t < COUT) {
        float mu  = sums[t] * (1.f / N_VOX);
        float var = sums[COUT + t] * (1.f / N_VOX) - mu*mu;
        float s = rsqrtf(var + 1e-3f) * gm[t];
        sc[t] = s;
        sh[t] = bt[t] - mu * s;
    }
    __syncthreads();
    for (int e = blockIdx.x*256 + t; e < N_VOX*COUT; e += gridDim.x*256) {
        int c = e % COUT;
        float v = preA[e] + preB[e];
        preA[e] = fmaxf(v * sc[c] + sh[c], 0.f);
    }
}

// ============ dense fill, float4 writes: out[b][c*8+z][y][x] ================
__global__ void k_dense(const float* __restrict__ feat, const int* __restrict__ gridP,
                        float* __restrict__ out) {
    int e4 = blockIdx.x*256 + threadIdx.x;
    if (e4 >= OUT_ELEMS/4) return;
    int e = e4 * 4;
    int x  = e % WW;                      // multiple of 4
    int y  = (e / WW) % HH;
    int cz = (e / (WW*HH)) % (128*DD);
    int b  = e / (WW*HH*128*DD);
    int c = cz >> 3, z = cz & 7;
    const int* gp = &gridP[((b*PD + z+1)*PH + (y+1))*PW + (x+1)];
    int g0 = gp[0], g1 = gp[1], g2 = gp[2], g3 = gp[3];
    float4 o;
    o.x = (g0 >= 0) ? feat[(size_t)g0*128 + c] : 0.f;
    o.y = (g1 >= 0) ? feat[(size_t)g1*128 + c] : 0.f;
    o.z = (g2 >= 0) ? feat[(size_t)g2*128 + c] : 0.f;
    o.w = (g3 >= 0) ? feat[(size_t)g3*128 + c] : 0.f;
    *(float4*)&out[e] = o;
}

// ============ host side ============
template<int CIN, int COUT, int NSPL>
static void run_block(const float* gm, const float* bt,
                      const int* nbrP, unsigned short* phi, const unsigned short* Wsw,
                      float* sums, float* preA, float* preB, bool last,
                      hipStream_t stream) {
    constexpr int SK   = 2;
    constexpr int NMB  = (N_VOX + 127) / 128;
    constexpr int NBLK = NMB * NSPL * SK;
    constexpr int GRID = ((NBLK + 7) / 8) * 8;
    k_conv_mfma<CIN, COUT, NSPL, SK><<<GRID, 256, 0, stream>>>(phi, nbrP, Wsw, preA, preB);
    k_bnstats2<COUT><<<128, 256, 0, stream>>>(preA, preB, sums);
    if (last) {
        k_bnapply_f32<COUT><<<512, 256, 0, stream>>>(preA, preB, sums, gm, bt);
    } else {
        k_bnapply_phi<COUT><<<512, 256, 0, stream>>>(preA, preB, sums, gm, bt, phi);
    }
}

extern "C" void kernel_launch(void* const* d_in, const int* in_sizes, int n_in,
                              void* d_out, int out_size, void* d_ws, size_t ws_size,
                              hipStream_t stream) {
    const float* vf    = (const float*)d_in[0];
    const int*   coors = (const int*)d_in[1];
    const float* wb[5] = {(const float*)d_in[3],  (const float*)d_in[7],
                          (const float*)d_in[11], (const float*)d_in[15],
                          (const float*)d_in[19]};
    const float* wsp[5]= {(const float*)d_in[4],  (const float*)d_in[8],
                          (const float*)d_in[12], (const float*)d_in[16],
                          (const float*)d_in[20]};
    const float* gm[5] = {(const float*)d_in[5],  (const float*)d_in[9],
                          (const float*)d_in[13], (const float*)d_in[17],
                          (const float*)d_in[21]};
    const float* bt[5] = {(const float*)d_in[6],  (const float*)d_in[10],
                          (const float*)d_in[14], (const float*)d_in[18],
                          (const float*)d_in[22]};

    // workspace bump allocator (256B aligned), ~92 MB total
    char* p = (char*)d_ws;
    auto alloc = [&](size_t bytes) {
        char* r = p;
        p += (bytes + 255) & ~(size_t)255;
        return r;
    };
    int*            flags   = (int*)           alloc((size_t)NCELL * 4);
    int*            scanout = (int*)           alloc((size_t)NCELL * 4);
    int*            bsums   = (int*)           alloc(512 * 4);
    int*            pos_of  = (int*)           alloc((size_t)N_VOX * 4);
    int*            vox_at  = (int*)           alloc((size_t)N_VOX * 4);
    int*            gridP   = (int*)           alloc((size_t)GRID_ELEMS * 4);
    int*            nbrP    = (int*)           alloc((size_t)KK * N_VOX * 4);
    unsigned short* Wsw0    = (unsigned short*)alloc((size_t)KK * 64  * 16  * 2);
    unsigned short* Wsw1    = (unsigned short*)alloc((size_t)KK * 64  * 32  * 2);
    unsigned short* Wsw2    = (unsigned short*)alloc((size_t)KK * 128 * 64  * 2);
    unsigned short* Wsw3    = (unsigned short*)alloc((size_t)KK * 256 * 64  * 2);
    unsigned short* Wsw4    = (unsigned short*)alloc((size_t)KK * 256 * 128 * 2);
    unsigned short* phi     = (unsigned short*)alloc((size_t)(N_VOX + 1) * 256 * 2);
    float*          sumsAll = (float*)         alloc(5 * 512 * 4);
    float*          preA    = (float*)         alloc((size_t)N_VOX * 128 * 4);
    float*          preB    = (float*)         alloc((size_t)N_VOX * 128 * 4);

    // ---- zero init (workspace re-poisoned to 0xAA before every timed call)
    hipMemsetAsync(flags, 0, (size_t)NCELL * 4, stream);
    hipMemsetAsync(gridP, 0xFF, (size_t)GRID_ELEMS * 4, stream);
    hipMemsetAsync(sumsAll, 0, 5 * 512 * 4, stream);

    // ---- all weight swizzles in one dispatch
    WswzArgs wa;
    for (int i = 0; i < 5; ++i) { wa.wb[i] = wb[i]; wa.ws[i] = wsp[i]; }
    wa.dst[0] = Wsw0; wa.dst[1] = Wsw1; wa.dst[2] = Wsw2; wa.dst[3] = Wsw3; wa.dst[4] = Wsw4;
    k_wswz_all<<<(1631232 + 255) / 256, 256, 0, stream>>>(wa);

    // ---- spatial permutation + rulebook
    k_flags<<<(N_VOX+255)/256, 256, 0, stream>>>(coors, flags);
    k_scan1<<<NCELL/1024, 256, 0, stream>>>(flags, scanout, bsums);
    k_scan2<<<1, 512, 0, stream>>>(bsums);
    k_pos  <<<(N_VOX+255)/256, 256, 0, stream>>>(coors, scanout, bsums, pos_of, vox_at);
    k_gridP<<<(N_VOX+255)/256, 256, 0, stream>>>(coors, pos_of, gridP);
    k_nbrP <<<(N_VOX+255)/256, 256, 0, stream>>>(coors, vox_at, gridP, nbrP);
    {
        int n = (N_VOX + 1) * 16;
        k_phi0<<<(n + 255) / 256, 256, 0, stream>>>(vf, vox_at, phi);
    }

    // ---- 5 KAN blocks (NSPL chosen for NFW=4 where possible; SK=2 TLP)
    run_block<16, 16,  1>(gm[0], bt[0], nbrP, phi, Wsw0, sumsAll + 0*512, preA, preB, false, stream);
    run_block<16, 32,  1>(gm[1], bt[1], nbrP, phi, Wsw1, sumsAll + 1*512, preA, preB, false, stream);
    run_block<32, 64,  1>(gm[2], bt[2], nbrP, phi, Wsw2, sumsAll + 2*512, preA, preB, false, stream);
    run_block<64, 64,  1>(gm[3], bt[3], nbrP, phi, Wsw3, sumsAll + 3*512, preA, preB, false, stream);
    run_block<64, 128, 2>(gm[4], bt[4], nbrP, phi, Wsw4, sumsAll + 4*512, preA, preB, true,  stream);

    // ---- dense output (preA holds final activated features)
    k_dense<<<(OUT_ELEMS/4 + 255)/256, 256, 0, stream>>>(preA, gridP, (float*)d_out);
}

// Round 9
// 737.920 us; speedup vs baseline: 1.2085x; 1.2085x over previous
//
#include <hip/hip_runtime.h>

#define N_VOX 50000
#define BATCH 2
#define DD 8
#define HH 160
#define WW 160
#define PD 10
#define PH 162
#define PW 162
#define KK 27
#define NCELL (BATCH*DD*HH*WW)         // 409600 = 400*1024
#define GRID_ELEMS (BATCH*PD*PH*PW)    // 524880
#define OUT_ELEMS (BATCH*128*DD*HH*WW) // 52,428,800

typedef __attribute__((ext_vector_type(8))) short short8v;
typedef __attribute__((ext_vector_type(4))) float float4v;

__device__ inline unsigned short f2bf(float f) {
    unsigned u = __float_as_uint(f);
    u += 0x7FFFu + ((u >> 16) & 1u);
    return (unsigned short)(u >> 16);
}

// ============ spatial sort: occupancy flags -> prefix sum -> permutation ====
__global__ void k_flags(const int* __restrict__ coors, int* __restrict__ flags) {
    int n = blockIdx.x * 256 + threadIdx.x;
    if (n >= N_VOX) return;
    int b = coors[n*4+0], z = coors[n*4+1], y = coors[n*4+2], x = coors[n*4+3];
    flags[((b*DD + z)*HH + y)*WW + x] = 1;
}

__global__ void k_scan1(const int* __restrict__ flags, int* __restrict__ scanout,
                        int* __restrict__ bsums) {
    __shared__ int s[256];
    int t = threadIdx.x, blk = blockIdx.x;
    int4 v = ((const int4*)(flags + blk*1024))[t];
    int tsum = v.x + v.y + v.z + v.w;
    s[t] = tsum; __syncthreads();
    for (int off = 1; off < 256; off <<= 1) {
        int x = (t >= off) ? s[t-off] : 0;
        __syncthreads(); s[t] += x; __syncthreads();
    }
    int excl = s[t] - tsum;
    int4 o; o.x = excl; o.y = excl + v.x; o.z = o.y + v.y; o.w = o.z + v.z;
    ((int4*)(scanout + blk*1024))[t] = o;
    if (t == 255) bsums[blk] = s[255];
}

__global__ void k_scan2(int* __restrict__ bsums) {
    __shared__ int s[512];
    int t = threadIdx.x;
    int orig = (t < 400) ? bsums[t] : 0;
    s[t] = orig; __syncthreads();
    for (int off = 1; off < 512; off <<= 1) {
        int x = (t >= off) ? s[t-off] : 0;
        __syncthreads(); s[t] += x; __syncthreads();
    }
    if (t < 400) bsums[t] = s[t] - orig;
}

__global__ void k_pos(const int* __restrict__ coors, const int* __restrict__ scanout,
                      const int* __restrict__ bsums, int* __restrict__ pos_of,
                      int* __restrict__ vox_at) {
    int n = blockIdx.x * 256 + threadIdx.x;
    if (n >= N_VOX) return;
    int b = coors[n*4+0], z = coors[n*4+1], y = coors[n*4+2], x = coors[n*4+3];
    int lin = ((b*DD + z)*HH + y)*WW + x;
    int pos = scanout[lin] + bsums[lin >> 10];
    pos_of[n] = pos;
    vox_at[pos] = n;
}

__global__ void k_gridP(const int* __restrict__ coors, const int* __restrict__ pos_of,
                        int* __restrict__ gridP) {
    int n = blockIdx.x * 256 + threadIdx.x;
    if (n >= N_VOX) return;
    int b = coors[n*4+0], z = coors[n*4+1], y = coors[n*4+2], x = coors[n*4+3];
    gridP[((b*PD + z+1)*PH + (y+1))*PW + (x+1)] = pos_of[n];
}

// iterate permuted index -> coalesced nbrP writes
__global__ void k_nbrP(const int* __restrict__ coors, const int* __restrict__ vox_at,
                       const int* __restrict__ gridP, int* __restrict__ nbrP) {
    int i = blockIdx.x * 256 + threadIdx.x;
    if (i >= N_VOX) return;
    int n = vox_at[i];
    int b = coors[n*4+0], z = coors[n*4+1]+1, y = coors[n*4+2]+1, x = coors[n*4+3]+1;
    int k = 0;
    for (int dz = -1; dz <= 1; ++dz)
        for (int dy = -1; dy <= 1; ++dy)
            for (int dx = -1; dx <= 1; ++dx) {
                int g = gridP[((b*PD + z+dz)*PH + (y+dy))*PW + (x+dx)];
                nbrP[k*N_VOX + i] = (g >= 0) ? g : N_VOX;
                ++k;
            }
}

// ============ phi: [N_VOX+1][4*CIN] bf16 (permuted rows); pad row = phi(0) ==
__global__ void k_phi0(const float* __restrict__ vf, const int* __restrict__ vox_at,
                       unsigned short* __restrict__ phi) {
    int e = blockIdx.x * 256 + threadIdx.x;
    if (e >= (N_VOX + 1) * 16) return;
    int i = e / 16, c = e % 16;
    float x = 0.f;
    if (i < N_VOX) x = vf[(size_t)vox_at[i] * 16 + c];
    float sig = 1.f / (1.f + __expf(-x));
    ushort4 p;
    p.x = f2bf(x * sig);
    p.y = f2bf(__expf(-(x + 1.f) * (x + 1.f)));
    p.z = f2bf(__expf(-x * x));
    p.w = f2bf(__expf(-(x - 1.f) * (x - 1.f)));
    *(ushort4*)&phi[(size_t)e * 4] = p;
}

// ============ all 5 layers' weight swizzle in ONE dispatch ============
struct WswzArgs {
    const float* wb[5];
    const float* ws[5];
    unsigned short* dst[5];
};
__global__ void k_wswz_all(WswzArgs a) {
    constexpr int off[6]   = {0, 27648, 82944, 304128, 746496, 1631232};
    constexpr int lgCI4[5] = {6, 6, 7, 8, 8};
    constexpr int lgCO[5]  = {4, 5, 6, 6, 7};
    int e = blockIdx.x * 256 + threadIdx.x;
    if (e >= off[5]) return;
    int L = 0;
    #pragma unroll
    for (int i = 1; i < 5; ++i) L += (e >= off[i]);
    int el = e - off[L];
    int CIN4 = 1 << lgCI4[L], COUT = 1 << lgCO[L], CIN = CIN4 >> 2;
    int j8   = el & 7;
    int rest = el >> 3;
    int o    = rest & (COUT - 1);
    int kb   = rest >> lgCO[L];
    int kabs = kb * 8 + j8;
    int k  = kabs >> lgCI4[L];
    int c4 = kabs & (CIN4 - 1);
    int c = c4 >> 2, jj = c4 & 3;
    float v = (jj == 0) ? a.wb[L][(k * CIN + c) * COUT + o]
                        : a.ws[L][((k * CIN + c) * 3 + (jj - 1)) * COUT + o];
    a.dst[L][el] = f2bf(v);
}

// ============ barrier-free MFMA conv: A+B reg-dbuf, sched_barrier-fenced ====
// Block (mb,h): 128 voxel rows x COUTH cols. Stage loop unrolled x2 with two
// named buffer sets; __builtin_amdgcn_sched_barrier(0) stops the scheduler
// from sinking the prefetch loads below the current stage's MFMAs (the R7
// collapse). Fused BN-stats epilogue into 8 contention-striped stat copies.
template<int CIN, int COUT, int NSPL>
__global__ __launch_bounds__(256) void k_conv_mfma(
    const unsigned short* __restrict__ phi,   // [(N_VOX+1), 4*CIN] bf16
    const int*            __restrict__ nbrP,  // [KK, N_VOX] permuted, pad = N_VOX
    const unsigned short* __restrict__ Wsw,   // [Ktot/8, COUT, 8] bf16
    float*                __restrict__ pre,   // [N_VOX, COUT]
    float*                __restrict__ sums)  // [8][256] per-layer stats copies
{
    constexpr int CIN4   = CIN * 4;
    constexpr int BK     = 64;
    constexpr int SPK    = CIN4 / BK;          // 1,1,2,4,4
    constexpr int NSTAGE = KK * SPK;
    constexpr int COUTH  = COUT / NSPL;
    constexpr int NFW    = COUTH / 16;         // 1,2,4,4,4
    constexpr int NMB    = (N_VOX + 127) / 128;
    constexpr int NBLK   = NMB * NSPL;
    constexpr int PERX   = (NBLK + 7) / 8;

    int lb = blockIdx.x;
    int linear = (lb & 7) * PERX + (lb >> 3);  // XCD swizzle
    if (linear >= NBLK) return;
    const int mb = linear / NSPL, h = linear % NSPL;

    const int t = threadIdx.x, lane = t & 63, wv = t >> 6;
    const int l15 = lane & 15, q = lane >> 4;
    const int base = mb * 128;
    const int vg0 = base + wv * 32 + l15, vg1 = vg0 + 16;
    const int ob = h * COUTH;

    // per-lane B base: kb = s*8 + kk*4 + q ; o = ob + nf*16 + l15
    const unsigned short* bp = Wsw + (size_t)(q * COUT + ob + l15) * 8;

    int rows[2], rowsN[2];
    short8v A0[2][2], A1[2][2];     // [kk][row-frag]
    short8v B0[2][NFW], B1[2][NFW]; // [kk][nf]

    auto loadB = [&](int sp, short8v (&Bb)[2][NFW]) {
        #pragma unroll
        for (int kk = 0; kk < 2; ++kk)
            #pragma unroll
            for (int nf = 0; nf < NFW; ++nf)
                Bb[kk][nf] = *(const short8v*)(bp +
                    ((size_t)(sp * 8 + kk * 4) * COUT + nf * 16) * 8);
    };
    // rotates rows/rowsN pipeline; call with strictly increasing sp
    auto loadA = [&](int sp, short8v (&Ab)[2][2]) {
        if (sp % SPK == 0) { rows[0] = rowsN[0]; rows[1] = rowsN[1]; }
        const int c4s = (sp % SPK) * BK;
        const unsigned short* p0 = phi + (size_t)rows[0] * CIN4 + c4s + q * 8;
        const unsigned short* p1 = phi + (size_t)rows[1] * CIN4 + c4s + q * 8;
        Ab[0][0] = *(const short8v*)p0;        Ab[0][1] = *(const short8v*)p1;
        Ab[1][0] = *(const short8v*)(p0 + 32); Ab[1][1] = *(const short8v*)(p1 + 32);
        if (sp % SPK == 0) {
            int k2 = sp / SPK + 1;
            if (k2 < KK) {
                rowsN[0] = (vg0 < N_VOX) ? nbrP[k2 * N_VOX + vg0] : N_VOX;
                rowsN[1] = (vg1 < N_VOX) ? nbrP[k2 * N_VOX + vg1] : N_VOX;
            }
        }
    };

    float4v acc[2][NFW];
    #pragma unroll
    for (int mi = 0; mi < 2; ++mi)
        #pragma unroll
        for (int nf = 0; nf < NFW; ++nf)
            acc[mi][nf] = (float4v){0.f, 0.f, 0.f, 0.f};

    auto domfma = [&](const short8v (&Ab)[2][2], const short8v (&Bb)[2][NFW]) {
        #pragma unroll
        for (int kk = 0; kk < 2; ++kk)
            #pragma unroll
            for (int nf = 0; nf < NFW; ++nf) {
                acc[0][nf] = __builtin_amdgcn_mfma_f32_16x16x32_bf16(Ab[kk][0], Bb[kk][nf], acc[0][nf], 0, 0, 0);
                acc[1][nf] = __builtin_amdgcn_mfma_f32_16x16x32_bf16(Ab[kk][1], Bb[kk][nf], acc[1][nf], 0, 0, 0);
            }
    };

    // --- pipeline init: stage 0 operands into buf0, rows for k=1 in rowsN
    rows[0]  = (vg0 < N_VOX) ? nbrP[vg0] : N_VOX;
    rows[1]  = (vg1 < N_VOX) ? nbrP[vg1] : N_VOX;
    rowsN[0] = (vg0 < N_VOX) ? nbrP[N_VOX + vg0] : N_VOX;
    rowsN[1] = (vg1 < N_VOX) ? nbrP[N_VOX + vg1] : N_VOX;
    loadB(0, B0);
    {
        const unsigned short* p0 = phi + (size_t)rows[0] * CIN4 + q * 8;
        const unsigned short* p1 = phi + (size_t)rows[1] * CIN4 + q * 8;
        A0[0][0] = *(const short8v*)p0;        A0[0][1] = *(const short8v*)p1;
        A0[1][0] = *(const short8v*)(p0 + 32); A0[1][1] = *(const short8v*)(p1 + 32);
    }

    // --- main loop, unrolled x2: prefetch fenced ABOVE current-stage MFMAs
    int s = 0;
    for (; s + 2 <= NSTAGE; s += 2) {
        loadB(s + 1, B1); loadA(s + 1, A1);
        __builtin_amdgcn_sched_barrier(0);   // loads for s+1 must issue first
        domfma(A0, B0);
        if (s + 2 < NSTAGE) { loadB(s + 2, B0); loadA(s + 2, A0); }
        __builtin_amdgcn_sched_barrier(0);   // loads for s+2 before s+1 MFMAs
        domfma(A1, B1);
    }
    if (s < NSTAGE) domfma(A0, B0);          // odd-NSTAGE tail (27-stage layers)

    // --- store (C/D layout: col=lane&15, row=(lane>>4)*4+r  [measured m89])
    #pragma unroll
    for (int mi = 0; mi < 2; ++mi)
        #pragma unroll
        for (int nf = 0; nf < NFW; ++nf)
            #pragma unroll
            for (int r = 0; r < 4; ++r) {
                int v = base + wv * 32 + mi * 16 + q * 4 + r;
                if (v < N_VOX)
                    pre[(size_t)v * COUT + ob + nf * 16 + l15] = acc[mi][nf][r];
            }

    // --- fused BN stats
    float* S = sums + (blockIdx.x & 7) * 256;
    #pragma unroll
    for (int nf = 0; nf < NFW; ++nf) {
        float s1 = 0.f, s2 = 0.f;
        #pragma unroll
        for (int mi = 0; mi < 2; ++mi)
            #pragma unroll
            for (int r = 0; r < 4; ++r) {
                int v = base + wv * 32 + mi * 16 + q * 4 + r;
                if (v < N_VOX) {
                    float a = acc[mi][nf][r];
                    s1 += a; s2 += a * a;
                }
            }
        s1 += __shfl_xor(s1, 16); s1 += __shfl_xor(s1, 32);
        s2 += __shfl_xor(s2, 16); s2 += __shfl_xor(s2, 32);
        if (q == 0) {
            atomicAdd(&S[ob + nf * 16 + l15], s1);
            atomicAdd(&S[COUT + ob + nf * 16 + l15], s2);
        }
    }
}

// ============ BN apply: finalize scale/shift in LDS once, grid-stride ======
template<int COUT>
__global__ void k_bnapply_phi(const float* __restrict__ pre, const float* __restrict__ sums,
                              const float* __restrict__ gm, const float* __restrict__ bt,
                              unsigned short* __restrict__ phi) {
    __shared__ float sc[COUT], sh[COUT];
    int t = threadIdx.x;
    if (t < COUT) {
        float s1 = 0.f, s2 = 0.f;
        #pragma unroll
        for (int xo = 0; xo < 8; ++xo) {
            s1 += sums[xo * 256 + t];
            s2 += sums[xo * 256 + COUT + t];
        }
        float mu  = s1 * (1.f / N_VOX);
        float var = s2 * (1.f / N_VOX) - mu*mu;
        float s = rsqrtf(var + 1e-3f) * gm[t];
        sc[t] = s;
        sh[t] = bt[t] - mu * s;
    }
    __syncthreads();
    int tot = (N_VOX + 1) * COUT;
    for (int e = blockIdx.x*256 + t; e < tot; e += gridDim.x*256) {
        int i = e / COUT, c = e % COUT;
        float x = 0.f;
        if (i < N_VOX) x = fmaxf(pre[(size_t)i*COUT + c] * sc[c] + sh[c], 0.f);
        float sig = 1.f / (1.f + __expf(-x));
        ushort4 p;
        p.x = f2bf(x * sig);
        p.y = f2bf(__expf(-(x + 1.f) * (x + 1.f)));
        p.z = f2bf(__expf(-x * x));
        p.w = f2bf(__expf(-(x - 1.f) * (x - 1.f)));
        *(ushort4*)&phi[(size_t)e * 4] = p;
    }
}

template<int COUT>
__global__ void k_bnapply_f32(float* __restrict__ pre, const float* __restrict__ sums,
                              const float* __restrict__ gm, const float* __restrict__ bt) {
    __shared__ float sc[COUT], sh[COUT];
    int t = threadIdx.x;
    if (t < COUT) {
        float s1 = 0.f, s2 = 0.f;
        #pragma unroll
        for (int xo = 0; xo < 8; ++xo) {
            s1 += sums[xo * 256 + t];
            s2 += sums[xo * 256 + COUT + t];
        }
        float mu  = s1 * (1.f / N_VOX);
        float var = s2 * (1.f / N_VOX) - mu*mu;
        float s = rsqrtf(var + 1e-3f) * gm[t];
        sc[t] = s;
        sh[t] = bt[t] - mu * s;
    }
    __syncthreads();
    for (int e = blockIdx.x*256 + t; e < N_VOX*COUT; e += gridDim.x*256) {
        int c = e % COUT;
        pre[e] = fmaxf(pre[e] * sc[c] + sh[c], 0.f);
    }
}

// ============ dense fill, float4 writes: out[b][c*8+z][y][x] ================
__global__ void k_dense(const float* __restrict__ feat, const int* __restrict__ gridP,
                        float* __restrict__ out) {
    int e4 = blockIdx.x*256 + threadIdx.x;
    if (e4 >= OUT_ELEMS/4) return;
    int e = e4 * 4;
    int x  = e % WW;                      // multiple of 4
    int y  = (e / WW) % HH;
    int cz = (e / (WW*HH)) % (128*DD);
    int b  = e / (WW*HH*128*DD);
    int c = cz >> 3, z = cz & 7;
    const int* gp = &gridP[((b*PD + z+1)*PH + (y+1))*PW + (x+1)];
    int g0 = gp[0], g1 = gp[1], g2 = gp[2], g3 = gp[3];
    float4 o;
    o.x = (g0 >= 0) ? feat[(size_t)g0*128 + c] : 0.f;
    o.y = (g1 >= 0) ? feat[(size_t)g1*128 + c] : 0.f;
    o.z = (g2 >= 0) ? feat[(size_t)g2*128 + c] : 0.f;
    o.w = (g3 >= 0) ? feat[(size_t)g3*128 + c] : 0.f;
    *(float4*)&out[e] = o;
}

// ============ host side ============
template<int CIN, int COUT, int NSPL>
static void run_block(const float* gm, const float* bt,
                      const int* nbrP, unsigned short* phi, const unsigned short* Wsw,
                      float* sums, float* pre, bool last, hipStream_t stream) {
    constexpr int NMB  = (N_VOX + 127) / 128;
    constexpr int NBLK = NMB * NSPL;
    constexpr int GRID = ((NBLK + 7) / 8) * 8;
    k_conv_mfma<CIN, COUT, NSPL><<<GRID, 256, 0, stream>>>(phi, nbrP, Wsw, pre, sums);
    if (last) {
        k_bnapply_f32<COUT><<<512, 256, 0, stream>>>(pre, sums, gm, bt);
    } else {
        k_bnapply_phi<COUT><<<512, 256, 0, stream>>>(pre, sums, gm, bt, phi);
    }
}

extern "C" void kernel_launch(void* const* d_in, const int* in_sizes, int n_in,
                              void* d_out, int out_size, void* d_ws, size_t ws_size,
                              hipStream_t stream) {
    const float* vf    = (const float*)d_in[0];
    const int*   coors = (const int*)d_in[1];
    const float* wb[5] = {(const float*)d_in[3],  (const float*)d_in[7],
                          (const float*)d_in[11], (const float*)d_in[15],
                          (const float*)d_in[19]};
    const float* wsp[5]= {(const float*)d_in[4],  (const float*)d_in[8],
                          (const float*)d_in[12], (const float*)d_in[16],
                          (const float*)d_in[20]};
    const float* gm[5] = {(const float*)d_in[5],  (const float*)d_in[9],
                          (const float*)d_in[13], (const float*)d_in[17],
                          (const float*)d_in[21]};
    const float* bt[5] = {(const float*)d_in[6],  (const float*)d_in[10],
                          (const float*)d_in[14], (const float*)d_in[18],
                          (const float*)d_in[22]};

    // workspace bump allocator (256B aligned), ~66 MB total
    char* p = (char*)d_ws;
    auto alloc = [&](size_t bytes) {
        char* r = p;
        p += (bytes + 255) & ~(size_t)255;
        return r;
    };
    int*            flags   = (int*)           alloc((size_t)NCELL * 4);
    int*            scanout = (int*)           alloc((size_t)NCELL * 4);
    int*            bsums   = (int*)           alloc(512 * 4);
    int*            pos_of  = (int*)           alloc((size_t)N_VOX * 4);
    int*            vox_at  = (int*)           alloc((size_t)N_VOX * 4);
    int*            gridP   = (int*)           alloc((size_t)GRID_ELEMS * 4);
    int*            nbrP    = (int*)           alloc((size_t)KK * N_VOX * 4);
    unsigned short* Wsw0    = (unsigned short*)alloc((size_t)KK * 64  * 16  * 2);
    unsigned short* Wsw1    = (unsigned short*)alloc((size_t)KK * 64  * 32  * 2);
    unsigned short* Wsw2    = (unsigned short*)alloc((size_t)KK * 128 * 64  * 2);
    unsigned short* Wsw3    = (unsigned short*)alloc((size_t)KK * 256 * 64  * 2);
    unsigned short* Wsw4    = (unsigned short*)alloc((size_t)KK * 256 * 128 * 2);
    unsigned short* phi     = (unsigned short*)alloc((size_t)(N_VOX + 1) * 256 * 2);
    float*          sumsAll = (float*)         alloc(5 * 8 * 256 * 4);
    float*          pre     = (float*)         alloc((size_t)N_VOX * 128 * 4);

    // ---- zero init (workspace re-poisoned to 0xAA before every timed call)
    hipMemsetAsync(flags, 0, (size_t)NCELL * 4, stream);
    hipMemsetAsync(gridP, 0xFF, (size_t)GRID_ELEMS * 4, stream);
    hipMemsetAsync(sumsAll, 0, 5 * 8 * 256 * 4, stream);

    // ---- all weight swizzles in one dispatch
    WswzArgs wa;
    for (int i = 0; i < 5; ++i) { wa.wb[i] = wb[i]; wa.ws[i] = wsp[i]; }
    wa.dst[0] = Wsw0; wa.dst[1] = Wsw1; wa.dst[2] = Wsw2; wa.dst[3] = Wsw3; wa.dst[4] = Wsw4;
    k_wswz_all<<<(1631232 + 255) / 256, 256, 0, stream>>>(wa);

    // ---- spatial permutation + rulebook
    k_flags<<<(N_VOX+255)/256, 256, 0, stream>>>(coors, flags);
    k_scan1<<<NCELL/1024, 256, 0, stream>>>(flags, scanout, bsums);
    k_scan2<<<1, 512, 0, stream>>>(bsums);
    k_pos  <<<(N_VOX+255)/256, 256, 0, stream>>>(coors, scanout, bsums, pos_of, vox_at);
    k_gridP<<<(N_VOX+255)/256, 256, 0, stream>>>(coors, pos_of, gridP);
    k_nbrP <<<(N_VOX+255)/256, 256, 0, stream>>>(coors, vox_at, gridP, nbrP);
    {
        int n = (N_VOX + 1) * 16;
        k_phi0<<<(n + 255) / 256, 256, 0, stream>>>(vf, vox_at, phi);
    }

    // ---- 5 KAN blocks (NFW=4 shapes where possible; no split-K)
    run_block<16, 16,  1>(gm[0], bt[0], nbrP, phi, Wsw0, sumsAll + 0*2048, pre, false, stream);
    run_block<16, 32,  1>(gm[1], bt[1], nbrP, phi, Wsw1, sumsAll + 1*2048, pre, false, stream);
    run_block<32, 64,  1>(gm[2], bt[2], nbrP, phi, Wsw2, sumsAll + 2*2048, pre, false, stream);
    run_block<64, 64,  1>(gm[3], bt[3], nbrP, phi, Wsw3, sumsAll + 3*2048, pre, false, stream);
    run_block<64, 128, 2>(gm[4], bt[4], nbrP, phi, Wsw4, sumsAll + 4*2048, pre, true,  stream);

    // ---- dense output
    k_dense<<<(OUT_ELEMS/4 + 255)/256, 256, 0, stream>>>(pre, gridP, (float*)d_out);
}